// Round 2
// baseline (131.011 us; speedup 1.0000x reference)
//
#include <hip/hip_runtime.h>

typedef _Float16 f16;
typedef _Float16 f16x8 __attribute__((ext_vector_type(8)));
typedef _Float16 f16x4 __attribute__((ext_vector_type(4)));
typedef float f32x4 __attribute__((ext_vector_type(4)));

#define MFMA16(a, b, c) __builtin_amdgcn_mfma_f32_16x16x32_f16(a, b, c, 0, 0, 0)

constexpr int Bn = 8, Sn = 2048, En = 1024, Hn = 64;
constexpr int Mn = Bn * Sn;  // 16384

// ---------------------------------------------------------------------------
// Kernel 0: one-time W fp32 -> fp16 repack.
// Wc layout: [kt=16][rr=192][c=64] f16, rr<64 -> Wq row rr, rr<128 -> Wk,
// rr<192 -> Wv; c = k within the 64-wide k-tile.
// ---------------------------------------------------------------------------
__global__ __launch_bounds__(256) void convw_kernel(
    const float* __restrict__ Wq, const float* __restrict__ Wk,
    const float* __restrict__ Wv, f16* __restrict__ Wc)
{
    const int h = blockIdx.x * 256 + threadIdx.x;  // 0..24575, 8 f16 each
    const int kt = h / 1536;
    const int rem = h - kt * 1536;
    const int rr = rem >> 3;
    const int c0 = (rem & 7) * 8;
    const int set = rr >> 6;
    const float* src = (set == 0 ? Wq : (set == 1 ? Wk : Wv))
                       + (size_t)(rr & 63) * En + kt * 64 + c0;
    float4 v0 = *reinterpret_cast<const float4*>(src);
    float4 v1 = *reinterpret_cast<const float4*>(src + 4);
    f16x8 o = {(f16)v0.x, (f16)v0.y, (f16)v0.z, (f16)v0.w,
               (f16)v1.x, (f16)v1.y, (f16)v1.z, (f16)v1.w};
    *reinterpret_cast<f16x8*>(Wc + (size_t)h * 8) = o;
}

// ---------------------------------------------------------------------------
// Kernel 1: QKV projection, barrier-free. 1024 WGs x 16 rows; wave w computes
// n-tiles w*3..w*3+2; B-fragments straight from L1/L2-resident fp16 Wc.
// ---------------------------------------------------------------------------
__global__ __launch_bounds__(256) void proj_kernel(
    const float* __restrict__ x, const f16* __restrict__ Wc,
    const float* __restrict__ bq, const float* __restrict__ bk,
    const float* __restrict__ bv,
    f16* __restrict__ qws, f16* __restrict__ kws, f16* __restrict__ vtws)
{
    const int tid = threadIdx.x;
    const int w = tid >> 6, l = tid & 63;
    const int l15 = l & 15, lhi = l >> 4;
    const int Mbase = blockIdx.x * 16;
    const float* xrow = x + (size_t)(Mbase + l15) * En;

    f32x4 acc[3];
#pragma unroll
    for (int i = 0; i < 3; ++i) acc[i] = (f32x4){0.f, 0.f, 0.f, 0.f};

    for (int kb = 0; kb < 16; ++kb) {
        f16x8 a[2];
#pragma unroll
        for (int kc = 0; kc < 2; ++kc) {
            const float* ap = xrow + kb * 64 + kc * 32 + lhi * 8;
            float4 v0 = *reinterpret_cast<const float4*>(ap);
            float4 v1 = *reinterpret_cast<const float4*>(ap + 4);
            a[kc] = (f16x8){(f16)v0.x, (f16)v0.y, (f16)v0.z, (f16)v0.w,
                            (f16)v1.x, (f16)v1.y, (f16)v1.z, (f16)v1.w};
        }
        const f16* wt = Wc + (size_t)kb * 12288;
#pragma unroll
        for (int i = 0; i < 3; ++i) {
            const int nt = w * 3 + i;
#pragma unroll
            for (int kc = 0; kc < 2; ++kc) {
                f16x8 bfrag = *reinterpret_cast<const f16x8*>(
                    wt + (nt * 16 + l15) * 64 + kc * 32 + lhi * 8);
                acc[i] = MFMA16(a[kc], bfrag, acc[i]);
            }
        }
    }

    const int batch = Mbase >> 11;
    const int r0 = Mbase + lhi * 4;
#pragma unroll
    for (int i = 0; i < 3; ++i) {
        const int nt = w * 3 + i;
        const int set = nt >> 2;
        const int h = (nt & 3) * 16 + l15;
        const float bias = (set == 0 ? bq : (set == 1 ? bk : bv))[h];
        if (set == 0) {
#pragma unroll
            for (int r = 0; r < 4; ++r)
                qws[(size_t)(r0 + r) * Hn + h] = (f16)(acc[i][r] + bias);
        } else if (set == 1) {
#pragma unroll
            for (int r = 0; r < 4; ++r)
                kws[(size_t)(r0 + r) * Hn + h] = (f16)(acc[i][r] + bias);
        } else {
            const int s0 = r0 & (Sn - 1);
            f16x4 hv = {(f16)(acc[i][0] + bias), (f16)(acc[i][1] + bias),
                        (f16)(acc[i][2] + bias), (f16)(acc[i][3] + bias)};
            *reinterpret_cast<f16x4*>(
                &vtws[(size_t)batch * Hn * Sn + (size_t)h * Sn + s0]) = hv;
        }
    }
}

// ---------------------------------------------------------------------------
// Kernel 2: causal flash attention, chunked. WG = (b, qtile16, chunk of
// <=32 key-tiles). 4 waves split the chunk; partials merged in LDS.
// j<64: single chunk -> write out directly. j>=64: write (m,l,O) slot.
// slot layout: [m(16) | l(16) | O(16x64)] = 1056 floats.
// ---------------------------------------------------------------------------
__global__ __launch_bounds__(256) void attn_kernel(
    const f16* __restrict__ qws, const f16* __restrict__ kws,
    const f16* __restrict__ vtws, float* __restrict__ out,
    float* __restrict__ slots)
{
    __shared__ f16 Plds[4][16 * 56];
    __shared__ float OL[4][16][64];
    __shared__ float mL[4][16];
    __shared__ float lL[4][16];

    const int tid = threadIdx.x;
    const int w = tid >> 6, l = tid & 63;
    const int l15 = l & 15, lhi = l >> 4;

    const int id = (blockIdx.x * 997) % 1536;
    int b, j, chunk;
    if (id < 1024) { b = id >> 7; j = id & 127; chunk = 0; }
    else { const int t = id - 1024; b = t >> 6; j = 64 + (t & 63); chunk = 1; }

    const int qbase = j * 16;
    const int nkt = (j + 2) >> 1;  // ceil((j+1)/2) key tiles of 32
    const int tstart = chunk * 32;
    const int tend = (tstart + 32 < nkt) ? tstart + 32 : nkt;

    const f16* qb = qws + (size_t)b * Sn * Hn;
    const f16* kb = kws + (size_t)b * Sn * Hn;
    const f16* vtb = vtws + (size_t)b * Hn * Sn;

    f16x8 qf[2];
#pragma unroll
    for (int kc = 0; kc < 2; ++kc)
        qf[kc] = *reinterpret_cast<const f16x8*>(
            &qb[(size_t)(qbase + l15) * Hn + kc * 32 + lhi * 8]);

    f32x4 O[4];
#pragma unroll
    for (int i = 0; i < 4; ++i) O[i] = (f32x4){0.f, 0.f, 0.f, 0.f};
    float m4[4], l4[4];
#pragma unroll
    for (int r = 0; r < 4; ++r) { m4[r] = -1e30f; l4[r] = 0.f; }

    for (int kt = tstart + w; kt < tend; kt += 4) {
        const int kbase = kt * 32;
        f32x4 Sv[2];
#pragma unroll
        for (int nt = 0; nt < 2; ++nt) {
            f32x4 sacc = (f32x4){0.f, 0.f, 0.f, 0.f};
#pragma unroll
            for (int kc = 0; kc < 2; ++kc) {
                f16x8 kf = *reinterpret_cast<const f16x8*>(
                    &kb[(size_t)(kbase + nt * 16 + l15) * Hn + kc * 32 + lhi * 8]);
                sacc = MFMA16(qf[kc], kf, sacc);
            }
            Sv[nt] = sacc;
        }
        float t[2][4];
#pragma unroll
        for (int nt = 0; nt < 2; ++nt) {
            const int key = kbase + nt * 16 + l15;
#pragma unroll
            for (int r = 0; r < 4; ++r) {
                const int qr = qbase + lhi * 4 + r;
                t[nt][r] = (key <= qr) ? Sv[nt][r] * 8.0f : -1e30f;
            }
        }
        float mnew[4], alpha[4];
#pragma unroll
        for (int r = 0; r < 4; ++r) {
            float mx = fmaxf(t[0][r], t[1][r]);
            mx = fmaxf(mx, __shfl_xor(mx, 1));
            mx = fmaxf(mx, __shfl_xor(mx, 2));
            mx = fmaxf(mx, __shfl_xor(mx, 4));
            mx = fmaxf(mx, __shfl_xor(mx, 8));
            mnew[r] = fmaxf(m4[r], mx);
            alpha[r] = __expf(m4[r] - mnew[r]);
            m4[r] = mnew[r];
        }
        float p[2][4];
#pragma unroll
        for (int r = 0; r < 4; ++r) {
            p[0][r] = (t[0][r] > -9e29f) ? __expf(t[0][r] - mnew[r]) : 0.f;
            p[1][r] = (t[1][r] > -9e29f) ? __expf(t[1][r] - mnew[r]) : 0.f;
            float s = p[0][r] + p[1][r];
            s += __shfl_xor(s, 1);
            s += __shfl_xor(s, 2);
            s += __shfl_xor(s, 4);
            s += __shfl_xor(s, 8);
            l4[r] = l4[r] * alpha[r] + s;
        }
#pragma unroll
        for (int nt = 0; nt < 2; ++nt)
#pragma unroll
            for (int r = 0; r < 4; ++r)
                Plds[w][(lhi * 4 + r) * 56 + nt * 16 + l15] = (f16)p[nt][r];
        f16x8 pa = *reinterpret_cast<const f16x8*>(&Plds[w][l15 * 56 + lhi * 8]);
#pragma unroll
        for (int nt = 0; nt < 4; ++nt) {
#pragma unroll
            for (int r = 0; r < 4; ++r) O[nt][r] *= alpha[r];
            f16x8 vf = *reinterpret_cast<const f16x8*>(
                &vtb[(size_t)(nt * 16 + l15) * Sn + kbase + lhi * 8]);
            O[nt] = MFMA16(pa, vf, O[nt]);
        }
    }

#pragma unroll
    for (int nt = 0; nt < 4; ++nt)
#pragma unroll
        for (int r = 0; r < 4; ++r)
            OL[w][lhi * 4 + r][nt * 16 + l15] = O[nt][r];
    if (l15 == 0) {
#pragma unroll
        for (int r = 0; r < 4; ++r) {
            mL[w][lhi * 4 + r] = m4[r];
            lL[w][lhi * 4 + r] = l4[r];
        }
    }
    __syncthreads();

    {
        const int row = tid >> 4, c0 = (tid & 15) * 4;
        float mg = fmaxf(fmaxf(mL[0][row], mL[1][row]),
                         fmaxf(mL[2][row], mL[3][row]));
        float den = 0.f;
        float num[4] = {0.f, 0.f, 0.f, 0.f};
#pragma unroll
        for (int ww = 0; ww < 4; ++ww) {
            float sc = __expf(mL[ww][row] - mg);
            den += lL[ww][row] * sc;
#pragma unroll
            for (int c = 0; c < 4; ++c) num[c] += OL[ww][row][c0 + c] * sc;
        }
        if (j < 64) {
            const float inv = 1.0f / den;
            float4 o = {num[0] * inv, num[1] * inv, num[2] * inv, num[3] * inv};
            *reinterpret_cast<float4*>(
                &out[((size_t)b * Sn + qbase + row) * Hn + c0]) = o;
        } else {
            float* sl = slots + (size_t)(chunk * 512 + b * 64 + (j - 64)) * 1056;
            float4 o = {num[0], num[1], num[2], num[3]};
            *reinterpret_cast<float4*>(&sl[32 + row * 64 + c0]) = o;
            if (c0 == 0) { sl[row] = mg; sl[16 + row] = den; }
        }
    }
}

// ---------------------------------------------------------------------------
// Kernel 3: merge the two chunk partials for qtiles j>=64.
// ---------------------------------------------------------------------------
__global__ __launch_bounds__(256) void comb_kernel(
    const float* __restrict__ slots, float* __restrict__ out)
{
    const int id = blockIdx.x;  // 0..511
    const int b = id >> 6, j = 64 + (id & 63);
    const float* s0 = slots + (size_t)(b * 64 + (j - 64)) * 1056;
    const float* s1 = s0 + (size_t)512 * 1056;
    const int tid = threadIdx.x;
    const int row = tid >> 4, c0 = (tid & 15) * 4;
    const float m0 = s0[row], l0 = s0[16 + row];
    const float m1 = s1[row], l1 = s1[16 + row];
    const float mg = fmaxf(m0, m1);
    const float a0 = __expf(m0 - mg), a1 = __expf(m1 - mg);
    const float inv = 1.0f / (l0 * a0 + l1 * a1);
    float4 o0 = *reinterpret_cast<const float4*>(&s0[32 + row * 64 + c0]);
    float4 o1 = *reinterpret_cast<const float4*>(&s1[32 + row * 64 + c0]);
    float4 o = {(o0.x * a0 + o1.x * a1) * inv, (o0.y * a0 + o1.y * a1) * inv,
                (o0.z * a0 + o1.z * a1) * inv, (o0.w * a0 + o1.w * a1) * inv};
    *reinterpret_cast<float4*>(
        &out[((size_t)b * Sn + j * 16 + row) * Hn + c0]) = o;
}

// ---------------------------------------------------------------------------
extern "C" void kernel_launch(void* const* d_in, const int* in_sizes, int n_in,
                              void* d_out, int out_size, void* d_ws, size_t ws_size,
                              hipStream_t stream) {
    const float* x  = (const float*)d_in[0];
    const float* Wk = (const float*)d_in[1];
    const float* bk = (const float*)d_in[2];
    const float* Wq = (const float*)d_in[3];
    const float* bq = (const float*)d_in[4];
    const float* Wv = (const float*)d_in[5];
    const float* bv = (const float*)d_in[6];

    f16* qws  = (f16*)d_ws;                    // 1,048,576 f16
    f16* kws  = qws + (size_t)Mn * Hn;         // 1,048,576 f16
    f16* vtws = kws + (size_t)Mn * Hn;         // 1,048,576 f16
    f16* Wc   = vtws + (size_t)Mn * Hn;        // 196,608 f16
    float* slots = (float*)(Wc + 196608);      // 1024 * 1056 f32 (~4.1 MB)

    convw_kernel<<<96, 256, 0, stream>>>(Wq, Wk, Wv, Wc);
    proj_kernel<<<1024, 256, 0, stream>>>(x, Wc, bq, bk, bv, qws, kws, vtws);
    attn_kernel<<<1536, 256, 0, stream>>>(qws, kws, vtws, (float*)d_out, slots);
    comb_kernel<<<512, 256, 0, stream>>>(slots, (float*)d_out);
}

// Round 3
// 104.039 us; speedup vs baseline: 1.2593x; 1.2593x over previous
//
#include <hip/hip_runtime.h>

typedef _Float16 f16;
typedef _Float16 f16x8 __attribute__((ext_vector_type(8)));
typedef _Float16 f16x4 __attribute__((ext_vector_type(4)));
typedef float f32x4 __attribute__((ext_vector_type(4)));

#define MFMA16(a, b, c) __builtin_amdgcn_mfma_f32_16x16x32_f16(a, b, c, 0, 0, 0)

constexpr int Bn = 8, Sn = 2048, En = 1024, Hn = 64;
constexpr int Mn = Bn * Sn;  // 16384

__device__ __forceinline__ void gload_lds16(const void* g, void* lds) {
    __builtin_amdgcn_global_load_lds(
        (const __attribute__((address_space(1))) void*)g,
        (__attribute__((address_space(3))) void*)lds, 16, 0, 0);
}

// ---------------------------------------------------------------------------
// Kernel 0: one-time W fp32 -> fp16 repack, PRE-SWIZZLED for proj's LDS.
// Logical layout: [kt=16][rr=192][c=64] f16; within each 128-B row the eight
// 16-B chunks are stored at chunk' = chunk ^ (rr & 7)  (XOR involution), so
// that a linear global_load_lds image + XOR-on-read is bank-conflict-free.
// ---------------------------------------------------------------------------
__global__ __launch_bounds__(256) void convw_kernel(
    const float* __restrict__ Wq, const float* __restrict__ Wk,
    const float* __restrict__ Wv, f16* __restrict__ Wc)
{
    const int h = blockIdx.x * 256 + threadIdx.x;  // 0..24575, one 16-B chunk
    const int kt = h / 1536;
    const int rem = h - kt * 1536;
    const int rr = rem >> 3;
    const int c = rem & 7;                 // logical chunk index (8 halves)
    const int set = rr >> 6;
    const float* src = (set == 0 ? Wq : (set == 1 ? Wk : Wv))
                       + (size_t)(rr & 63) * En + kt * 64 + c * 8;
    float4 v0 = *reinterpret_cast<const float4*>(src);
    float4 v1 = *reinterpret_cast<const float4*>(src + 4);
    f16x8 o = {(f16)v0.x, (f16)v0.y, (f16)v0.z, (f16)v0.w,
               (f16)v1.x, (f16)v1.y, (f16)v1.z, (f16)v1.w};
    const int cs = c ^ (rr & 7);           // pre-swizzle (rule #21)
    *reinterpret_cast<f16x8*>(Wc + (size_t)kt * 12288 + rr * 64 + cs * 8) = o;
}

// ---------------------------------------------------------------------------
// Kernel 1: QKV projection. 1024 WGs x 16 rows. W tile [192][64] f16 staged
// per k-step via global_load_lds (linear dest, pre-swizzled source); B-frag
// ds_read_b128 applies the same XOR -> max 2-way bank aliasing (free).
// ---------------------------------------------------------------------------
__global__ __launch_bounds__(256) void proj_kernel(
    const float* __restrict__ x, const f16* __restrict__ Wc,
    const float* __restrict__ bq, const float* __restrict__ bk,
    const float* __restrict__ bv,
    f16* __restrict__ qws, f16* __restrict__ kws, f16* __restrict__ vtws)
{
    __shared__ f16 Wlds[12288];  // [192][64] linear (24 KB)
    const int tid = threadIdx.x;
    const int w = tid >> 6, l = tid & 63;
    const int l15 = l & 15, lhi = l >> 4;
    const int Mbase = blockIdx.x * 16;
    const float* xrow = x + (size_t)(Mbase + l15) * En;
    char* ldsb = reinterpret_cast<char*>(Wlds);

    f32x4 acc[3];
#pragma unroll
    for (int i = 0; i < 3; ++i) acc[i] = (f32x4){0.f, 0.f, 0.f, 0.f};

    for (int kb = 0; kb < 16; ++kb) {
        if (kb) __syncthreads();  // protect LDS before overwrite
        // stage W tile: 24576 B = 6 rounds x 256 thr x 16 B
        const f16* wt = Wc + (size_t)kb * 12288;
#pragma unroll
        for (int r = 0; r < 6; ++r) {
            gload_lds16(wt + (r * 256 + tid) * 8,
                        ldsb + (r * 4096 + w * 1024));
        }
        // x fragments (issue before barrier; drain overlaps stage)
        float4 xa[2][2];
#pragma unroll
        for (int kc = 0; kc < 2; ++kc) {
            const float* ap = xrow + kb * 64 + kc * 32 + lhi * 8;
            xa[kc][0] = *reinterpret_cast<const float4*>(ap);
            xa[kc][1] = *reinterpret_cast<const float4*>(ap + 4);
        }
        __syncthreads();  // drains vmcnt(0): stage + x complete

        f16x8 a[2];
#pragma unroll
        for (int kc = 0; kc < 2; ++kc)
            a[kc] = (f16x8){(f16)xa[kc][0].x, (f16)xa[kc][0].y,
                            (f16)xa[kc][0].z, (f16)xa[kc][0].w,
                            (f16)xa[kc][1].x, (f16)xa[kc][1].y,
                            (f16)xa[kc][1].z, (f16)xa[kc][1].w};
#pragma unroll
        for (int i = 0; i < 3; ++i) {
            const int row16 = (w * 3 + i) * 16 + l15;
#pragma unroll
            for (int kc = 0; kc < 2; ++kc) {
                const int addr = row16 * 128
                               + ((kc * 64 + lhi * 16) ^ ((l15 & 7) << 4));
                f16x8 bfrag = *reinterpret_cast<const f16x8*>(ldsb + addr);
                acc[i] = MFMA16(a[kc], bfrag, acc[i]);
            }
        }
    }

    const int batch = Mbase >> 11;
    const int r0 = Mbase + lhi * 4;
#pragma unroll
    for (int i = 0; i < 3; ++i) {
        const int nt = w * 3 + i;
        const int set = nt >> 2;
        const int h = (nt & 3) * 16 + l15;
        const float bias = (set == 0 ? bq : (set == 1 ? bk : bv))[h];
        if (set == 0) {
#pragma unroll
            for (int r = 0; r < 4; ++r)
                qws[(size_t)(r0 + r) * Hn + h] = (f16)(acc[i][r] + bias);
        } else if (set == 1) {
#pragma unroll
            for (int r = 0; r < 4; ++r)
                kws[(size_t)(r0 + r) * Hn + h] = (f16)(acc[i][r] + bias);
        } else {
            const int s0 = r0 & (Sn - 1);
            f16x4 hv = {(f16)(acc[i][0] + bias), (f16)(acc[i][1] + bias),
                        (f16)(acc[i][2] + bias), (f16)(acc[i][3] + bias)};
            *reinterpret_cast<f16x4*>(
                &vtws[(size_t)batch * Hn * Sn + (size_t)h * Sn + s0]) = hv;
        }
    }
}

// ---------------------------------------------------------------------------
// Kernel 2: causal flash attention, chunked (unchanged from round 2).
// ---------------------------------------------------------------------------
__global__ __launch_bounds__(256) void attn_kernel(
    const f16* __restrict__ qws, const f16* __restrict__ kws,
    const f16* __restrict__ vtws, float* __restrict__ out,
    float* __restrict__ slots)
{
    __shared__ f16 Plds[4][16 * 56];
    __shared__ float OL[4][16][64];
    __shared__ float mL[4][16];
    __shared__ float lL[4][16];

    const int tid = threadIdx.x;
    const int w = tid >> 6, l = tid & 63;
    const int l15 = l & 15, lhi = l >> 4;

    const int id = (blockIdx.x * 997) % 1536;
    int b, j, chunk;
    if (id < 1024) { b = id >> 7; j = id & 127; chunk = 0; }
    else { const int t = id - 1024; b = t >> 6; j = 64 + (t & 63); chunk = 1; }

    const int qbase = j * 16;
    const int nkt = (j + 2) >> 1;
    const int tstart = chunk * 32;
    const int tend = (tstart + 32 < nkt) ? tstart + 32 : nkt;

    const f16* qb = qws + (size_t)b * Sn * Hn;
    const f16* kb = kws + (size_t)b * Sn * Hn;
    const f16* vtb = vtws + (size_t)b * Hn * Sn;

    f16x8 qf[2];
#pragma unroll
    for (int kc = 0; kc < 2; ++kc)
        qf[kc] = *reinterpret_cast<const f16x8*>(
            &qb[(size_t)(qbase + l15) * Hn + kc * 32 + lhi * 8]);

    f32x4 O[4];
#pragma unroll
    for (int i = 0; i < 4; ++i) O[i] = (f32x4){0.f, 0.f, 0.f, 0.f};
    float m4[4], l4[4];
#pragma unroll
    for (int r = 0; r < 4; ++r) { m4[r] = -1e30f; l4[r] = 0.f; }

    for (int kt = tstart + w; kt < tend; kt += 4) {
        const int kbase = kt * 32;
        f32x4 Sv[2];
#pragma unroll
        for (int nt = 0; nt < 2; ++nt) {
            f32x4 sacc = (f32x4){0.f, 0.f, 0.f, 0.f};
#pragma unroll
            for (int kc = 0; kc < 2; ++kc) {
                f16x8 kf = *reinterpret_cast<const f16x8*>(
                    &kb[(size_t)(kbase + nt * 16 + l15) * Hn + kc * 32 + lhi * 8]);
                sacc = MFMA16(qf[kc], kf, sacc);
            }
            Sv[nt] = sacc;
        }
        float t[2][4];
#pragma unroll
        for (int nt = 0; nt < 2; ++nt) {
            const int key = kbase + nt * 16 + l15;
#pragma unroll
            for (int r = 0; r < 4; ++r) {
                const int qr = qbase + lhi * 4 + r;
                t[nt][r] = (key <= qr) ? Sv[nt][r] * 8.0f : -1e30f;
            }
        }
        float mnew[4], alpha[4];
#pragma unroll
        for (int r = 0; r < 4; ++r) {
            float mx = fmaxf(t[0][r], t[1][r]);
            mx = fmaxf(mx, __shfl_xor(mx, 1));
            mx = fmaxf(mx, __shfl_xor(mx, 2));
            mx = fmaxf(mx, __shfl_xor(mx, 4));
            mx = fmaxf(mx, __shfl_xor(mx, 8));
            mnew[r] = fmaxf(m4[r], mx);
            alpha[r] = __expf(m4[r] - mnew[r]);
            m4[r] = mnew[r];
        }
        float p[2][4];
#pragma unroll
        for (int r = 0; r < 4; ++r) {
            p[0][r] = (t[0][r] > -9e29f) ? __expf(t[0][r] - mnew[r]) : 0.f;
            p[1][r] = (t[1][r] > -9e29f) ? __expf(t[1][r] - mnew[r]) : 0.f;
            float s = p[0][r] + p[1][r];
            s += __shfl_xor(s, 1);
            s += __shfl_xor(s, 2);
            s += __shfl_xor(s, 4);
            s += __shfl_xor(s, 8);
            l4[r] = l4[r] * alpha[r] + s;
        }
#pragma unroll
        for (int nt = 0; nt < 2; ++nt)
#pragma unroll
            for (int r = 0; r < 4; ++r)
                Plds[w][(lhi * 4 + r) * 56 + nt * 16 + l15] = (f16)p[nt][r];
        f16x8 pa = *reinterpret_cast<const f16x8*>(&Plds[w][l15 * 56 + lhi * 8]);
#pragma unroll
        for (int nt = 0; nt < 4; ++nt) {
#pragma unroll
            for (int r = 0; r < 4; ++r) O[nt][r] *= alpha[r];
            f16x8 vf = *reinterpret_cast<const f16x8*>(
                &vtb[(size_t)(nt * 16 + l15) * Sn + kbase + lhi * 8]);
            O[nt] = MFMA16(pa, vf, O[nt]);
        }
    }

#pragma unroll
    for (int nt = 0; nt < 4; ++nt)
#pragma unroll
        for (int r = 0; r < 4; ++r)
            OL[w][lhi * 4 + r][nt * 16 + l15] = O[nt][r];
    if (l15 == 0) {
#pragma unroll
        for (int r = 0; r < 4; ++r) {
            mL[w][lhi * 4 + r] = m4[r];
            lL[w][lhi * 4 + r] = l4[r];
        }
    }
    __syncthreads();

    {
        const int row = tid >> 4, c0 = (tid & 15) * 4;
        float mg = fmaxf(fmaxf(mL[0][row], mL[1][row]),
                         fmaxf(mL[2][row], mL[3][row]));
        float den = 0.f;
        float num[4] = {0.f, 0.f, 0.f, 0.f};
#pragma unroll
        for (int ww = 0; ww < 4; ++ww) {
            float sc = __expf(mL[ww][row] - mg);
            den += lL[ww][row] * sc;
#pragma unroll
            for (int c = 0; c < 4; ++c) num[c] += OL[ww][row][c0 + c] * sc;
        }
        if (j < 64) {
            const float inv = 1.0f / den;
            float4 o = {num[0] * inv, num[1] * inv, num[2] * inv, num[3] * inv};
            *reinterpret_cast<float4*>(
                &out[((size_t)b * Sn + qbase + row) * Hn + c0]) = o;
        } else {
            float* sl = slots + (size_t)(chunk * 512 + b * 64 + (j - 64)) * 1056;
            float4 o = {num[0], num[1], num[2], num[3]};
            *reinterpret_cast<float4*>(&sl[32 + row * 64 + c0]) = o;
            if (c0 == 0) { sl[row] = mg; sl[16 + row] = den; }
        }
    }
}

// ---------------------------------------------------------------------------
// Kernel 3: merge the two chunk partials for qtiles j>=64 (unchanged).
// ---------------------------------------------------------------------------
__global__ __launch_bounds__(256) void comb_kernel(
    const float* __restrict__ slots, float* __restrict__ out)
{
    const int id = blockIdx.x;  // 0..511
    const int b = id >> 6, j = 64 + (id & 63);
    const float* s0 = slots + (size_t)(b * 64 + (j - 64)) * 1056;
    const float* s1 = s0 + (size_t)512 * 1056;
    const int tid = threadIdx.x;
    const int row = tid >> 4, c0 = (tid & 15) * 4;
    const float m0 = s0[row], l0 = s0[16 + row];
    const float m1 = s1[row], l1 = s1[16 + row];
    const float mg = fmaxf(m0, m1);
    const float a0 = __expf(m0 - mg), a1 = __expf(m1 - mg);
    const float inv = 1.0f / (l0 * a0 + l1 * a1);
    float4 o0 = *reinterpret_cast<const float4*>(&s0[32 + row * 64 + c0]);
    float4 o1 = *reinterpret_cast<const float4*>(&s1[32 + row * 64 + c0]);
    float4 o = {(o0.x * a0 + o1.x * a1) * inv, (o0.y * a0 + o1.y * a1) * inv,
                (o0.z * a0 + o1.z * a1) * inv, (o0.w * a0 + o1.w * a1) * inv};
    *reinterpret_cast<float4*>(
        &out[((size_t)b * Sn + j * 16 + row) * Hn + c0]) = o;
}

// ---------------------------------------------------------------------------
extern "C" void kernel_launch(void* const* d_in, const int* in_sizes, int n_in,
                              void* d_out, int out_size, void* d_ws, size_t ws_size,
                              hipStream_t stream) {
    const float* x  = (const float*)d_in[0];
    const float* Wk = (const float*)d_in[1];
    const float* bk = (const float*)d_in[2];
    const float* Wq = (const float*)d_in[3];
    const float* bq = (const float*)d_in[4];
    const float* Wv = (const float*)d_in[5];
    const float* bv = (const float*)d_in[6];

    f16* qws  = (f16*)d_ws;                    // 1,048,576 f16
    f16* kws  = qws + (size_t)Mn * Hn;         // 1,048,576 f16
    f16* vtws = kws + (size_t)Mn * Hn;         // 1,048,576 f16
    f16* Wc   = vtws + (size_t)Mn * Hn;        // 196,608 f16 (swizzled)
    float* slots = (float*)(Wc + 196608);      // 1024 * 1056 f32 (~4.1 MB)

    convw_kernel<<<96, 256, 0, stream>>>(Wq, Wk, Wv, Wc);
    proj_kernel<<<1024, 256, 0, stream>>>(x, Wc, bq, bk, bv, qws, kws, vtws);
    attn_kernel<<<1536, 256, 0, stream>>>(qws, kws, vtws, (float*)d_out, slots);
    comb_kernel<<<512, 256, 0, stream>>>(slots, (float*)d_out);
}

// Round 4
// 89.306 us; speedup vs baseline: 1.4670x; 1.1650x over previous
//
#include <hip/hip_runtime.h>

typedef _Float16 f16;
typedef _Float16 f16x8 __attribute__((ext_vector_type(8)));
typedef _Float16 f16x4 __attribute__((ext_vector_type(4)));
typedef float f32x4 __attribute__((ext_vector_type(4)));

#define MFMA16(a, b, c) __builtin_amdgcn_mfma_f32_16x16x32_f16(a, b, c, 0, 0, 0)

constexpr int Bn = 8, Sn = 2048, En = 1024, Hn = 64;
constexpr int Mn = Bn * Sn;  // 16384

__device__ __forceinline__ void gload_lds16(const void* g, void* lds) {
    __builtin_amdgcn_global_load_lds(
        (const __attribute__((address_space(1))) void*)g,
        (__attribute__((address_space(3))) void*)lds, 16, 0, 0);
}
__device__ __forceinline__ void wait_vm7() {
    asm volatile("s_waitcnt vmcnt(7)" ::: "memory");
    __builtin_amdgcn_sched_barrier(0);
}
__device__ __forceinline__ void wait_vm0() {
    asm volatile("s_waitcnt vmcnt(0)" ::: "memory");
    __builtin_amdgcn_sched_barrier(0);
}
__device__ __forceinline__ void barrier_raw() {
    __builtin_amdgcn_s_barrier();
    __builtin_amdgcn_sched_barrier(0);
}

// ---------------------------------------------------------------------------
// Kernel 0: one-time W fp32 -> fp16 repack, PRE-SWIZZLED (unchanged).
// Logical [kt=16][rr=192][c=64] f16; 16-B chunk stored at c ^ (rr & 7).
// ---------------------------------------------------------------------------
__global__ __launch_bounds__(256) void convw_kernel(
    const float* __restrict__ Wq, const float* __restrict__ Wk,
    const float* __restrict__ Wv, f16* __restrict__ Wc)
{
    const int h = blockIdx.x * 256 + threadIdx.x;  // 0..24575, one 16-B chunk
    const int kt = h / 1536;
    const int rem = h - kt * 1536;
    const int rr = rem >> 3;
    const int c = rem & 7;
    const int set = rr >> 6;
    const float* src = (set == 0 ? Wq : (set == 1 ? Wk : Wv))
                       + (size_t)(rr & 63) * En + kt * 64 + c * 8;
    float4 v0 = *reinterpret_cast<const float4*>(src);
    float4 v1 = *reinterpret_cast<const float4*>(src + 4);
    f16x8 o = {(f16)v0.x, (f16)v0.y, (f16)v0.z, (f16)v0.w,
               (f16)v1.x, (f16)v1.y, (f16)v1.z, (f16)v1.w};
    const int cs = c ^ (rr & 7);
    *reinterpret_cast<f16x8*>(Wc + (size_t)kt * 12288 + rr * 64 + cs * 8) = o;
}

// ---------------------------------------------------------------------------
// Kernel 1: QKV projection. grid=256, 512 threads (8 waves), BM=64.
// Wave w: row-tile (w&3)*16, n-half (w>>2) -> 6 n-tiles. W double-buffered
// in LDS via global_load_lds; pipeline uses raw s_barrier + counted
// s_waitcnt vmcnt(7) so next-step loads stay in flight across barriers.
// ---------------------------------------------------------------------------
__global__ __launch_bounds__(512) void proj_kernel(
    const float* __restrict__ x, const f16* __restrict__ Wc,
    const float* __restrict__ bq, const float* __restrict__ bk,
    const float* __restrict__ bv,
    f16* __restrict__ qws, f16* __restrict__ kws, f16* __restrict__ vtws)
{
    __shared__ f16 Wlds[2 * 12288];  // 2 x [192][64] linear (48 KB)
    const int tid = threadIdx.x;
    const int w = tid >> 6, l = tid & 63;
    const int l15 = l & 15, lhi = l >> 4;
    const int rt = w & 3, nh = w >> 2;
    const int Mbase = blockIdx.x * 64;
    const float* xrow = x + (size_t)(Mbase + rt * 16 + l15) * En;
    char* ldsb = reinterpret_cast<char*>(Wlds);

    f32x4 acc[6];
#pragma unroll
    for (int i = 0; i < 6; ++i) acc[i] = (f32x4){0.f, 0.f, 0.f, 0.f};

    // --- staging: 24 KB = 3 rounds x 8 waves x 1024 B ---
#define STAGE(buf, kb)                                                        \
    {                                                                         \
        const f16* wt_ = Wc + (size_t)(kb) * 12288;                           \
        _Pragma("unroll")                                                     \
        for (int r_ = 0; r_ < 3; ++r_)                                        \
            gload_lds16(wt_ + r_ * 4096 + w * 512 + l * 8,                    \
                        ldsb + (buf) * 24576 + r_ * 8192 + w * 1024);         \
    }

#define XLOAD(xr, kb)                                                         \
    {                                                                         \
        _Pragma("unroll")                                                     \
        for (int kc_ = 0; kc_ < 2; ++kc_) {                                   \
            const float* ap_ = xrow + (kb) * 64 + kc_ * 32 + lhi * 8;         \
            xr[kc_][0] = *reinterpret_cast<const float4*>(ap_);               \
            xr[kc_][1] = *reinterpret_cast<const float4*>(ap_ + 4);           \
        }                                                                     \
    }

#define COMPUTE(buf, xr)                                                      \
    {                                                                         \
        f16x8 a_[2];                                                          \
        _Pragma("unroll")                                                     \
        for (int kc_ = 0; kc_ < 2; ++kc_)                                     \
            a_[kc_] = (f16x8){(f16)xr[kc_][0].x, (f16)xr[kc_][0].y,           \
                              (f16)xr[kc_][0].z, (f16)xr[kc_][0].w,           \
                              (f16)xr[kc_][1].x, (f16)xr[kc_][1].y,           \
                              (f16)xr[kc_][1].z, (f16)xr[kc_][1].w};          \
        _Pragma("unroll")                                                     \
        for (int i_ = 0; i_ < 6; ++i_) {                                      \
            const int row16_ = (nh * 6 + i_) * 16 + l15;                      \
            _Pragma("unroll")                                                 \
            for (int kc_ = 0; kc_ < 2; ++kc_) {                               \
                const int addr_ = (buf) * 24576 + row16_ * 128                \
                    + ((kc_ * 64 + lhi * 16) ^ ((l15 & 7) << 4));             \
                f16x8 b_ = *reinterpret_cast<const f16x8*>(ldsb + addr_);     \
                acc[i_] = MFMA16(a_[kc_], b_, acc[i_]);                       \
            }                                                                 \
        }                                                                     \
    }

    float4 xA[2][2], xB[2][2];
    STAGE(0, 0);
    XLOAD(xA, 0);
    for (int kb = 0; kb < 14; kb += 2) {
        STAGE(1, kb + 1);
        XLOAD(xB, kb + 1);
        wait_vm7();      // step kb's 7 loads complete (kb+1's may fly)
        barrier_raw();   // all waves' stage of buf0 done
        COMPUTE(0, xA);
        barrier_raw();   // all waves done reading buf0
        STAGE(0, kb + 2);
        XLOAD(xA, kb + 2);
        wait_vm7();
        barrier_raw();
        COMPUTE(1, xB);
        barrier_raw();
    }
    // kb = 14, 15 tail
    STAGE(1, 15);
    XLOAD(xB, 15);
    wait_vm7();
    barrier_raw();
    COMPUTE(0, xA);
    barrier_raw();
    wait_vm0();
    barrier_raw();
    COMPUTE(1, xB);
#undef STAGE
#undef XLOAD
#undef COMPUTE

    const int batch = Mbase >> 11;
    const int r0 = Mbase + rt * 16 + lhi * 4;
#pragma unroll
    for (int i = 0; i < 6; ++i) {
        const int nt = nh * 6 + i;
        const int set = nt >> 2;
        const int h = (nt & 3) * 16 + l15;
        const float bias = (set == 0 ? bq : (set == 1 ? bk : bv))[h];
        if (set == 0) {
#pragma unroll
            for (int r = 0; r < 4; ++r)
                qws[(size_t)(r0 + r) * Hn + h] = (f16)(acc[i][r] + bias);
        } else if (set == 1) {
#pragma unroll
            for (int r = 0; r < 4; ++r)
                kws[(size_t)(r0 + r) * Hn + h] = (f16)(acc[i][r] + bias);
        } else {
            const int s0 = r0 & (Sn - 1);
            f16x4 hv = {(f16)(acc[i][0] + bias), (f16)(acc[i][1] + bias),
                        (f16)(acc[i][2] + bias), (f16)(acc[i][3] + bias)};
            *reinterpret_cast<f16x4*>(
                &vtws[(size_t)batch * Hn * Sn + (size_t)h * Sn + s0]) = hv;
        }
    }
}

// ---------------------------------------------------------------------------
// Kernel 2: causal flash attention, chunked (unchanged).
// ---------------------------------------------------------------------------
__global__ __launch_bounds__(256) void attn_kernel(
    const f16* __restrict__ qws, const f16* __restrict__ kws,
    const f16* __restrict__ vtws, float* __restrict__ out,
    float* __restrict__ slots)
{
    __shared__ f16 Plds[4][16 * 56];
    __shared__ float OL[4][16][64];
    __shared__ float mL[4][16];
    __shared__ float lL[4][16];

    const int tid = threadIdx.x;
    const int w = tid >> 6, l = tid & 63;
    const int l15 = l & 15, lhi = l >> 4;

    const int id = (blockIdx.x * 997) % 1536;
    int b, j, chunk;
    if (id < 1024) { b = id >> 7; j = id & 127; chunk = 0; }
    else { const int t = id - 1024; b = t >> 6; j = 64 + (t & 63); chunk = 1; }

    const int qbase = j * 16;
    const int nkt = (j + 2) >> 1;
    const int tstart = chunk * 32;
    const int tend = (tstart + 32 < nkt) ? tstart + 32 : nkt;

    const f16* qb = qws + (size_t)b * Sn * Hn;
    const f16* kb = kws + (size_t)b * Sn * Hn;
    const f16* vtb = vtws + (size_t)b * Hn * Sn;

    f16x8 qf[2];
#pragma unroll
    for (int kc = 0; kc < 2; ++kc)
        qf[kc] = *reinterpret_cast<const f16x8*>(
            &qb[(size_t)(qbase + l15) * Hn + kc * 32 + lhi * 8]);

    f32x4 O[4];
#pragma unroll
    for (int i = 0; i < 4; ++i) O[i] = (f32x4){0.f, 0.f, 0.f, 0.f};
    float m4[4], l4[4];
#pragma unroll
    for (int r = 0; r < 4; ++r) { m4[r] = -1e30f; l4[r] = 0.f; }

    for (int kt = tstart + w; kt < tend; kt += 4) {
        const int kbase = kt * 32;
        f32x4 Sv[2];
#pragma unroll
        for (int nt = 0; nt < 2; ++nt) {
            f32x4 sacc = (f32x4){0.f, 0.f, 0.f, 0.f};
#pragma unroll
            for (int kc = 0; kc < 2; ++kc) {
                f16x8 kf = *reinterpret_cast<const f16x8*>(
                    &kb[(size_t)(kbase + nt * 16 + l15) * Hn + kc * 32 + lhi * 8]);
                sacc = MFMA16(qf[kc], kf, sacc);
            }
            Sv[nt] = sacc;
        }
        float t[2][4];
#pragma unroll
        for (int nt = 0; nt < 2; ++nt) {
            const int key = kbase + nt * 16 + l15;
#pragma unroll
            for (int r = 0; r < 4; ++r) {
                const int qr = qbase + lhi * 4 + r;
                t[nt][r] = (key <= qr) ? Sv[nt][r] * 8.0f : -1e30f;
            }
        }
        float mnew[4], alpha[4];
#pragma unroll
        for (int r = 0; r < 4; ++r) {
            float mx = fmaxf(t[0][r], t[1][r]);
            mx = fmaxf(mx, __shfl_xor(mx, 1));
            mx = fmaxf(mx, __shfl_xor(mx, 2));
            mx = fmaxf(mx, __shfl_xor(mx, 4));
            mx = fmaxf(mx, __shfl_xor(mx, 8));
            mnew[r] = fmaxf(m4[r], mx);
            alpha[r] = __expf(m4[r] - mnew[r]);
            m4[r] = mnew[r];
        }
        float p[2][4];
#pragma unroll
        for (int r = 0; r < 4; ++r) {
            p[0][r] = (t[0][r] > -9e29f) ? __expf(t[0][r] - mnew[r]) : 0.f;
            p[1][r] = (t[1][r] > -9e29f) ? __expf(t[1][r] - mnew[r]) : 0.f;
            float s = p[0][r] + p[1][r];
            s += __shfl_xor(s, 1);
            s += __shfl_xor(s, 2);
            s += __shfl_xor(s, 4);
            s += __shfl_xor(s, 8);
            l4[r] = l4[r] * alpha[r] + s;
        }
#pragma unroll
        for (int nt = 0; nt < 2; ++nt)
#pragma unroll
            for (int r = 0; r < 4; ++r)
                Plds[w][(lhi * 4 + r) * 56 + nt * 16 + l15] = (f16)p[nt][r];
        f16x8 pa = *reinterpret_cast<const f16x8*>(&Plds[w][l15 * 56 + lhi * 8]);
#pragma unroll
        for (int nt = 0; nt < 4; ++nt) {
#pragma unroll
            for (int r = 0; r < 4; ++r) O[nt][r] *= alpha[r];
            f16x8 vf = *reinterpret_cast<const f16x8*>(
                &vtb[(size_t)(nt * 16 + l15) * Sn + kbase + lhi * 8]);
            O[nt] = MFMA16(pa, vf, O[nt]);
        }
    }

#pragma unroll
    for (int nt = 0; nt < 4; ++nt)
#pragma unroll
        for (int r = 0; r < 4; ++r)
            OL[w][lhi * 4 + r][nt * 16 + l15] = O[nt][r];
    if (l15 == 0) {
#pragma unroll
        for (int r = 0; r < 4; ++r) {
            mL[w][lhi * 4 + r] = m4[r];
            lL[w][lhi * 4 + r] = l4[r];
        }
    }
    __syncthreads();

    {
        const int row = tid >> 4, c0 = (tid & 15) * 4;
        float mg = fmaxf(fmaxf(mL[0][row], mL[1][row]),
                         fmaxf(mL[2][row], mL[3][row]));
        float den = 0.f;
        float num[4] = {0.f, 0.f, 0.f, 0.f};
#pragma unroll
        for (int ww = 0; ww < 4; ++ww) {
            float sc = __expf(mL[ww][row] - mg);
            den += lL[ww][row] * sc;
#pragma unroll
            for (int c = 0; c < 4; ++c) num[c] += OL[ww][row][c0 + c] * sc;
        }
        if (j < 64) {
            const float inv = 1.0f / den;
            float4 o = {num[0] * inv, num[1] * inv, num[2] * inv, num[3] * inv};
            *reinterpret_cast<float4*>(
                &out[((size_t)b * Sn + qbase + row) * Hn + c0]) = o;
        } else {
            float* sl = slots + (size_t)(chunk * 512 + b * 64 + (j - 64)) * 1056;
            float4 o = {num[0], num[1], num[2], num[3]};
            *reinterpret_cast<float4*>(&sl[32 + row * 64 + c0]) = o;
            if (c0 == 0) { sl[row] = mg; sl[16 + row] = den; }
        }
    }
}

// ---------------------------------------------------------------------------
// Kernel 3: merge chunk partials for qtiles j>=64 (unchanged).
// ---------------------------------------------------------------------------
__global__ __launch_bounds__(256) void comb_kernel(
    const float* __restrict__ slots, float* __restrict__ out)
{
    const int id = blockIdx.x;  // 0..511
    const int b = id >> 6, j = 64 + (id & 63);
    const float* s0 = slots + (size_t)(b * 64 + (j - 64)) * 1056;
    const float* s1 = s0 + (size_t)512 * 1056;
    const int tid = threadIdx.x;
    const int row = tid >> 4, c0 = (tid & 15) * 4;
    const float m0 = s0[row], l0 = s0[16 + row];
    const float m1 = s1[row], l1 = s1[16 + row];
    const float mg = fmaxf(m0, m1);
    const float a0 = __expf(m0 - mg), a1 = __expf(m1 - mg);
    const float inv = 1.0f / (l0 * a0 + l1 * a1);
    float4 o0 = *reinterpret_cast<const float4*>(&s0[32 + row * 64 + c0]);
    float4 o1 = *reinterpret_cast<const float4*>(&s1[32 + row * 64 + c0]);
    float4 o = {(o0.x * a0 + o1.x * a1) * inv, (o0.y * a0 + o1.y * a1) * inv,
                (o0.z * a0 + o1.z * a1) * inv, (o0.w * a0 + o1.w * a1) * inv};
    *reinterpret_cast<float4*>(
        &out[((size_t)b * Sn + j * 16 + row) * Hn + c0]) = o;
}

// ---------------------------------------------------------------------------
extern "C" void kernel_launch(void* const* d_in, const int* in_sizes, int n_in,
                              void* d_out, int out_size, void* d_ws, size_t ws_size,
                              hipStream_t stream) {
    const float* x  = (const float*)d_in[0];
    const float* Wk = (const float*)d_in[1];
    const float* bk = (const float*)d_in[2];
    const float* Wq = (const float*)d_in[3];
    const float* bq = (const float*)d_in[4];
    const float* Wv = (const float*)d_in[5];
    const float* bv = (const float*)d_in[6];

    f16* qws  = (f16*)d_ws;                    // 1,048,576 f16
    f16* kws  = qws + (size_t)Mn * Hn;         // 1,048,576 f16
    f16* vtws = kws + (size_t)Mn * Hn;         // 1,048,576 f16
    f16* Wc   = vtws + (size_t)Mn * Hn;        // 196,608 f16 (swizzled)
    float* slots = (float*)(Wc + 196608);      // 1024 * 1056 f32 (~4.1 MB)

    convw_kernel<<<96, 256, 0, stream>>>(Wq, Wk, Wv, Wc);
    proj_kernel<<<256, 512, 0, stream>>>(x, Wc, bq, bk, bv, qws, kws, vtws);
    attn_kernel<<<1536, 256, 0, stream>>>(qws, kws, vtws, (float*)d_out, slots);
    comb_kernel<<<512, 256, 0, stream>>>(slots, (float*)d_out);
}

// Round 5
// 86.914 us; speedup vs baseline: 1.5074x; 1.0275x over previous
//
#include <hip/hip_runtime.h>

typedef _Float16 f16;
typedef _Float16 f16x8 __attribute__((ext_vector_type(8)));
typedef _Float16 f16x4 __attribute__((ext_vector_type(4)));
typedef float f32x4 __attribute__((ext_vector_type(4)));

#define MFMA16(a, b, c) __builtin_amdgcn_mfma_f32_16x16x32_f16(a, b, c, 0, 0, 0)

constexpr int Bn = 8, Sn = 2048, En = 1024, Hn = 64;
constexpr int Mn = Bn * Sn;  // 16384

__device__ __forceinline__ void gload_lds16(const void* g, void* lds) {
    __builtin_amdgcn_global_load_lds(
        (const __attribute__((address_space(1))) void*)g,
        (__attribute__((address_space(3))) void*)lds, 16, 0, 0);
}
__device__ __forceinline__ void wait_vm7() {
    asm volatile("s_waitcnt vmcnt(7)" ::: "memory");
    __builtin_amdgcn_sched_barrier(0);
}
__device__ __forceinline__ void wait_vm0() {
    asm volatile("s_waitcnt vmcnt(0)" ::: "memory");
    __builtin_amdgcn_sched_barrier(0);
}
__device__ __forceinline__ void barrier_raw() {
    __builtin_amdgcn_s_barrier();
    __builtin_amdgcn_sched_barrier(0);
}

// ---------------------------------------------------------------------------
// Kernel 0: one-time W fp32 -> fp16 repack, PRE-SWIZZLED (unchanged).
// ---------------------------------------------------------------------------
__global__ __launch_bounds__(256) void convw_kernel(
    const float* __restrict__ Wq, const float* __restrict__ Wk,
    const float* __restrict__ Wv, f16* __restrict__ Wc)
{
    const int h = blockIdx.x * 256 + threadIdx.x;
    const int kt = h / 1536;
    const int rem = h - kt * 1536;
    const int rr = rem >> 3;
    const int c = rem & 7;
    const int set = rr >> 6;
    const float* src = (set == 0 ? Wq : (set == 1 ? Wk : Wv))
                       + (size_t)(rr & 63) * En + kt * 64 + c * 8;
    float4 v0 = *reinterpret_cast<const float4*>(src);
    float4 v1 = *reinterpret_cast<const float4*>(src + 4);
    f16x8 o = {(f16)v0.x, (f16)v0.y, (f16)v0.z, (f16)v0.w,
               (f16)v1.x, (f16)v1.y, (f16)v1.z, (f16)v1.w};
    const int cs = c ^ (rr & 7);
    *reinterpret_cast<f16x8*>(Wc + (size_t)kt * 12288 + rr * 64 + cs * 8) = o;
}

// ---------------------------------------------------------------------------
// Kernel 1: QKV projection (unchanged from round 4).
// ---------------------------------------------------------------------------
__global__ __launch_bounds__(512) void proj_kernel(
    const float* __restrict__ x, const f16* __restrict__ Wc,
    const float* __restrict__ bq, const float* __restrict__ bk,
    const float* __restrict__ bv,
    f16* __restrict__ qws, f16* __restrict__ kws, f16* __restrict__ vtws)
{
    __shared__ f16 Wlds[2 * 12288];
    const int tid = threadIdx.x;
    const int w = tid >> 6, l = tid & 63;
    const int l15 = l & 15, lhi = l >> 4;
    const int rt = w & 3, nh = w >> 2;
    const int Mbase = blockIdx.x * 64;
    const float* xrow = x + (size_t)(Mbase + rt * 16 + l15) * En;
    char* ldsb = reinterpret_cast<char*>(Wlds);

    f32x4 acc[6];
#pragma unroll
    for (int i = 0; i < 6; ++i) acc[i] = (f32x4){0.f, 0.f, 0.f, 0.f};

#define STAGE(buf, kb)                                                        \
    {                                                                         \
        const f16* wt_ = Wc + (size_t)(kb) * 12288;                           \
        _Pragma("unroll")                                                     \
        for (int r_ = 0; r_ < 3; ++r_)                                        \
            gload_lds16(wt_ + r_ * 4096 + w * 512 + l * 8,                    \
                        ldsb + (buf) * 24576 + r_ * 8192 + w * 1024);         \
    }

#define XLOAD(xr, kb)                                                         \
    {                                                                         \
        _Pragma("unroll")                                                     \
        for (int kc_ = 0; kc_ < 2; ++kc_) {                                   \
            const float* ap_ = xrow + (kb) * 64 + kc_ * 32 + lhi * 8;         \
            xr[kc_][0] = *reinterpret_cast<const float4*>(ap_);               \
            xr[kc_][1] = *reinterpret_cast<const float4*>(ap_ + 4);           \
        }                                                                     \
    }

#define COMPUTE(buf, xr)                                                      \
    {                                                                         \
        f16x8 a_[2];                                                          \
        _Pragma("unroll")                                                     \
        for (int kc_ = 0; kc_ < 2; ++kc_)                                     \
            a_[kc_] = (f16x8){(f16)xr[kc_][0].x, (f16)xr[kc_][0].y,           \
                              (f16)xr[kc_][0].z, (f16)xr[kc_][0].w,           \
                              (f16)xr[kc_][1].x, (f16)xr[kc_][1].y,           \
                              (f16)xr[kc_][1].z, (f16)xr[kc_][1].w};          \
        _Pragma("unroll")                                                     \
        for (int i_ = 0; i_ < 6; ++i_) {                                      \
            const int row16_ = (nh * 6 + i_) * 16 + l15;                      \
            _Pragma("unroll")                                                 \
            for (int kc_ = 0; kc_ < 2; ++kc_) {                               \
                const int addr_ = (buf) * 24576 + row16_ * 128                \
                    + ((kc_ * 64 + lhi * 16) ^ ((l15 & 7) << 4));             \
                f16x8 b_ = *reinterpret_cast<const f16x8*>(ldsb + addr_);     \
                acc[i_] = MFMA16(a_[kc_], b_, acc[i_]);                       \
            }                                                                 \
        }                                                                     \
    }

    float4 xA[2][2], xB[2][2];
    STAGE(0, 0);
    XLOAD(xA, 0);
    for (int kb = 0; kb < 14; kb += 2) {
        STAGE(1, kb + 1);
        XLOAD(xB, kb + 1);
        wait_vm7();
        barrier_raw();
        COMPUTE(0, xA);
        barrier_raw();
        STAGE(0, kb + 2);
        XLOAD(xA, kb + 2);
        wait_vm7();
        barrier_raw();
        COMPUTE(1, xB);
        barrier_raw();
    }
    STAGE(1, 15);
    XLOAD(xB, 15);
    wait_vm7();
    barrier_raw();
    COMPUTE(0, xA);
    barrier_raw();
    wait_vm0();
    barrier_raw();
    COMPUTE(1, xB);
#undef STAGE
#undef XLOAD
#undef COMPUTE

    const int batch = Mbase >> 11;
    const int r0 = Mbase + rt * 16 + lhi * 4;
#pragma unroll
    for (int i = 0; i < 6; ++i) {
        const int nt = nh * 6 + i;
        const int set = nt >> 2;
        const int h = (nt & 3) * 16 + l15;
        const float bias = (set == 0 ? bq : (set == 1 ? bk : bv))[h];
        if (set == 0) {
#pragma unroll
            for (int r = 0; r < 4; ++r)
                qws[(size_t)(r0 + r) * Hn + h] = (f16)(acc[i][r] + bias);
        } else if (set == 1) {
#pragma unroll
            for (int r = 0; r < 4; ++r)
                kws[(size_t)(r0 + r) * Hn + h] = (f16)(acc[i][r] + bias);
        } else {
            const int s0 = r0 & (Sn - 1);
            f16x4 hv = {(f16)(acc[i][0] + bias), (f16)(acc[i][1] + bias),
                        (f16)(acc[i][2] + bias), (f16)(acc[i][3] + bias)};
            *reinterpret_cast<f16x4*>(
                &vtws[(size_t)batch * Hn * Sn + (size_t)h * Sn + s0]) = hv;
        }
    }
}

// ---------------------------------------------------------------------------
// Kernel 2: causal flash attention, fully wave-independent.
// Unit = (b, qtile j, chunk of <=8 key-tiles). 4608 units, 64-thread WGs.
// Group g = j>>4: every j in group g has exactly g+1 chunks.
// g==0: direct output write. g>=1: partial slot (m,l f32 + O f16, 544 f32).
// Dense slot id = b*560 + 8(g-1)(g+2) + (j-16g)*(g+1) + chunk.
// ---------------------------------------------------------------------------
__global__ __launch_bounds__(64) void attn_kernel(
    const f16* __restrict__ qws, const f16* __restrict__ kws,
    const f16* __restrict__ vtws, float* __restrict__ out,
    float* __restrict__ slots)
{
    __shared__ f16 Plds[16 * 56];
    const int l = threadIdx.x;
    const int l15 = l & 15, lhi = l >> 4;

    const int u = (int)(((unsigned)blockIdx.x * 997u) % 4608u);
    const int b = u / 576;
    const int t = u - b * 576;
    int g = 0;
#pragma unroll
    for (int gg = 1; gg < 8; ++gg)
        if (t >= 8 * gg * (gg + 1)) g = gg;
    const int rg = t - 8 * g * (g + 1);
    const int jj = rg / (g + 1);
    const int chunk = rg - jj * (g + 1);
    const int j = 16 * g + jj;

    const int qbase = j * 16;
    const int nkt = (j + 2) >> 1;
    const int tstart = chunk * 8;
    const int tend = (tstart + 8 < nkt) ? tstart + 8 : nkt;

    const f16* qb = qws + (size_t)b * Sn * Hn;
    const f16* kb = kws + (size_t)b * Sn * Hn;
    const f16* vtb = vtws + (size_t)b * Hn * Sn;

    f16x8 qf[2];
#pragma unroll
    for (int kc = 0; kc < 2; ++kc)
        qf[kc] = *reinterpret_cast<const f16x8*>(
            &qb[(size_t)(qbase + l15) * Hn + kc * 32 + lhi * 8]);

    f32x4 O[4];
#pragma unroll
    for (int i = 0; i < 4; ++i) O[i] = (f32x4){0.f, 0.f, 0.f, 0.f};
    float m4[4], l4[4];
#pragma unroll
    for (int r = 0; r < 4; ++r) { m4[r] = -1e30f; l4[r] = 0.f; }

    for (int kt = tstart; kt < tend; ++kt) {
        const int kbase = kt * 32;
        f32x4 Sv[2];
#pragma unroll
        for (int nt = 0; nt < 2; ++nt) {
            f32x4 sacc = (f32x4){0.f, 0.f, 0.f, 0.f};
#pragma unroll
            for (int kc = 0; kc < 2; ++kc) {
                f16x8 kf = *reinterpret_cast<const f16x8*>(
                    &kb[(size_t)(kbase + nt * 16 + l15) * Hn + kc * 32 + lhi * 8]);
                sacc = MFMA16(qf[kc], kf, sacc);
            }
            Sv[nt] = sacc;
        }
        float tv[2][4];
#pragma unroll
        for (int nt = 0; nt < 2; ++nt) {
            const int key = kbase + nt * 16 + l15;
#pragma unroll
            for (int r = 0; r < 4; ++r) {
                const int qr = qbase + lhi * 4 + r;
                tv[nt][r] = (key <= qr) ? Sv[nt][r] * 8.0f : -1e30f;
            }
        }
        float mnew[4], alpha[4];
#pragma unroll
        for (int r = 0; r < 4; ++r) {
            float mx = fmaxf(tv[0][r], tv[1][r]);
            mx = fmaxf(mx, __shfl_xor(mx, 1));
            mx = fmaxf(mx, __shfl_xor(mx, 2));
            mx = fmaxf(mx, __shfl_xor(mx, 4));
            mx = fmaxf(mx, __shfl_xor(mx, 8));
            mnew[r] = fmaxf(m4[r], mx);
            alpha[r] = __expf(m4[r] - mnew[r]);
            m4[r] = mnew[r];
        }
        float p[2][4];
#pragma unroll
        for (int r = 0; r < 4; ++r) {
            p[0][r] = (tv[0][r] > -9e29f) ? __expf(tv[0][r] - mnew[r]) : 0.f;
            p[1][r] = (tv[1][r] > -9e29f) ? __expf(tv[1][r] - mnew[r]) : 0.f;
            float s = p[0][r] + p[1][r];
            s += __shfl_xor(s, 1);
            s += __shfl_xor(s, 2);
            s += __shfl_xor(s, 4);
            s += __shfl_xor(s, 8);
            l4[r] = l4[r] * alpha[r] + s;
        }
#pragma unroll
        for (int nt = 0; nt < 2; ++nt)
#pragma unroll
            for (int r = 0; r < 4; ++r)
                Plds[(lhi * 4 + r) * 56 + nt * 16 + l15] = (f16)p[nt][r];
        f16x8 pa = *reinterpret_cast<const f16x8*>(&Plds[l15 * 56 + lhi * 8]);
#pragma unroll
        for (int nt = 0; nt < 4; ++nt) {
#pragma unroll
            for (int r = 0; r < 4; ++r) O[nt][r] *= alpha[r];
            f16x8 vf = *reinterpret_cast<const f16x8*>(
                &vtb[(size_t)(nt * 16 + l15) * Sn + kbase + lhi * 8]);
            O[nt] = MFMA16(pa, vf, O[nt]);
        }
    }

    if (g == 0) {
        // single chunk: normalize and write output directly from registers
#pragma unroll
        for (int r = 0; r < 4; ++r) {
            const float inv = 1.0f / l4[r];
            const size_t rowoff = ((size_t)b * Sn + qbase + lhi * 4 + r) * Hn;
#pragma unroll
            for (int nt = 0; nt < 4; ++nt)
                out[rowoff + nt * 16 + l15] = O[nt][r] * inv;
        }
    } else {
        float* sl = slots + (size_t)(b * 560 + 8 * (g - 1) * (g + 2)
                                     + jj * (g + 1) + chunk) * 544;
        f16* so = reinterpret_cast<f16*>(sl + 32);
#pragma unroll
        for (int r = 0; r < 4; ++r) {
            const int row = lhi * 4 + r;
            if (l15 == 0) { sl[row] = m4[r]; sl[16 + row] = l4[r]; }
#pragma unroll
            for (int nt = 0; nt < 4; ++nt)
                so[row * 64 + nt * 16 + l15] = (f16)O[nt][r];
        }
    }
}

// ---------------------------------------------------------------------------
// Kernel 3: merge up to g+1 chunk partials for qtiles j>=16.
// grid = 8 batches x 112 qtiles = 896 WGs x 256 threads.
// ---------------------------------------------------------------------------
__global__ __launch_bounds__(256) void comb_kernel(
    const float* __restrict__ slots, float* __restrict__ out)
{
    const int id = blockIdx.x;
    const int b = id / 112, jj = id - b * 112;
    const int j = 16 + jj;
    const int g = j >> 4;
    const int nch = g + 1;
    const float* base = slots + (size_t)(b * 560 + 8 * (g - 1) * (g + 2)
                                         + (j - 16 * g) * (g + 1)) * 544;
    const int tid = threadIdx.x;
    const int row = tid >> 4, c0 = (tid & 15) * 4;

    float mg = -1e30f;
    for (int c = 0; c < nch; ++c) mg = fmaxf(mg, base[c * 544 + row]);
    float den = 0.f;
    float num[4] = {0.f, 0.f, 0.f, 0.f};
    for (int c = 0; c < nch; ++c) {
        const float* sl = base + c * 544;
        const float a = __expf(sl[row] - mg);
        den += sl[16 + row] * a;
        const f16* so = reinterpret_cast<const f16*>(sl + 32);
        f16x4 ov = *reinterpret_cast<const f16x4*>(so + row * 64 + c0);
        num[0] += (float)ov[0] * a;
        num[1] += (float)ov[1] * a;
        num[2] += (float)ov[2] * a;
        num[3] += (float)ov[3] * a;
    }
    const float inv = 1.0f / den;
    float4 o = {num[0] * inv, num[1] * inv, num[2] * inv, num[3] * inv};
    *reinterpret_cast<float4*>(
        &out[((size_t)b * Sn + j * 16 + row) * Hn + c0]) = o;
}

// ---------------------------------------------------------------------------
extern "C" void kernel_launch(void* const* d_in, const int* in_sizes, int n_in,
                              void* d_out, int out_size, void* d_ws, size_t ws_size,
                              hipStream_t stream) {
    const float* x  = (const float*)d_in[0];
    const float* Wk = (const float*)d_in[1];
    const float* bk = (const float*)d_in[2];
    const float* Wq = (const float*)d_in[3];
    const float* bq = (const float*)d_in[4];
    const float* Wv = (const float*)d_in[5];
    const float* bv = (const float*)d_in[6];

    f16* qws  = (f16*)d_ws;                    // 1,048,576 f16 (2 MB)
    f16* kws  = qws + (size_t)Mn * Hn;         // 2 MB
    f16* vtws = kws + (size_t)Mn * Hn;         // 2 MB
    f16* Wc   = vtws + (size_t)Mn * Hn;        // 384 KB (swizzled)
    float* slots = (float*)(Wc + 196608);      // 4480 * 544 f32 (~9.8 MB)

    convw_kernel<<<96, 256, 0, stream>>>(Wq, Wk, Wv, Wc);
    proj_kernel<<<256, 512, 0, stream>>>(x, Wc, bq, bk, bv, qws, kws, vtws);
    attn_kernel<<<4608, 64, 0, stream>>>(qws, kws, vtws, (float*)d_out, slots);
    comb_kernel<<<896, 256, 0, stream>>>(slots, (float*)d_out);
}